// Round 3
// baseline (656.204 us; speedup 1.0000x reference)
//
#include <hip/hip_runtime.h>
#include <hip/hip_bf16.h>

typedef unsigned short u16;
typedef __attribute__((ext_vector_type(8))) short short8;  // 8 bf16 (4 VGPRs)
typedef __attribute__((ext_vector_type(4))) float f32x4;

#define BATCH 8
#define CH 256
#define NPIX 4096
#define KD 32   // C/8

static __device__ __forceinline__ u16 f2bf(float f) {
  union { __hip_bfloat16 h; u16 u; } cv;
  cv.h = __float2bfloat16(f);
  return cv.u;
}

// ---------------------------------------------------------------------------
// Kernel 1: projections. x [B][C][N] f32 -> fT/gT [B][N][32] bf16, hh [B][C][N] bf16
// Block: 256 threads, one batch x 32-pixel tile. x tile in LDS, broadcast reads.
// ---------------------------------------------------------------------------
__global__ __launch_bounds__(256) void proj_kernel(
    const float* __restrict__ x,
    const float* __restrict__ Wf, const float* __restrict__ bfp,
    const float* __restrict__ Wg, const float* __restrict__ bgp,
    const float* __restrict__ Wh, const float* __restrict__ bhp,
    u16* __restrict__ fT, u16* __restrict__ gT, u16* __restrict__ hhb)
{
  __shared__ float xs[CH][36];
  const int b  = blockIdx.x >> 7;
  const int n0 = (blockIdx.x & 127) * 32;
  const int t  = threadIdx.x;

  const float* xb = x + ((size_t)b * CH) * NPIX + n0;
  #pragma unroll
  for (int kk = 0; kk < 8; ++kk) {
    int v = kk * 256 + t;
    int c = v >> 3, p4 = v & 7;
    float4 d = *(const float4*)(xb + (size_t)c * NPIX + p4 * 4);
    *(float4*)&xs[c][p4 * 4] = d;
  }
  __syncthreads();

  const int o = t;
  float acch[32];
  #pragma unroll
  for (int p = 0; p < 32; ++p) acch[p] = bhp[o];

  const int o2 = t & 63;
  const int oo = o2 & 31;
  const bool isf = o2 < 32;
  const float* Wfg = isf ? Wf : Wg;
  const float bias2 = isf ? bfp[oo] : bgp[oo];
  const int pg = (t >> 6) * 8;
  float accf[8];
  #pragma unroll
  for (int p = 0; p < 8; ++p) accf[p] = bias2;

  const float* whr  = Wh  + o * CH;
  const float* wfgr = Wfg + oo * CH;
  for (int c = 0; c < CH; ++c) {
    float wh = whr[c];
    float wf = wfgr[c];
    #pragma unroll
    for (int p4 = 0; p4 < 8; ++p4) {
      float4 xv = *(const float4*)&xs[c][p4 * 4];
      acch[p4*4+0] = fmaf(wh, xv.x, acch[p4*4+0]);
      acch[p4*4+1] = fmaf(wh, xv.y, acch[p4*4+1]);
      acch[p4*4+2] = fmaf(wh, xv.z, acch[p4*4+2]);
      acch[p4*4+3] = fmaf(wh, xv.w, acch[p4*4+3]);
    }
    #pragma unroll
    for (int p = 0; p < 8; ++p) accf[p] = fmaf(wf, xs[c][pg + p], accf[p]);
  }

  u16* hrow = hhb + ((size_t)b * CH + o) * NPIX + n0;
  #pragma unroll
  for (int q = 0; q < 4; ++q) {
    uint4 u;
    u.x = f2bf(acch[q*8+0]) | ((unsigned)f2bf(acch[q*8+1]) << 16);
    u.y = f2bf(acch[q*8+2]) | ((unsigned)f2bf(acch[q*8+3]) << 16);
    u.z = f2bf(acch[q*8+4]) | ((unsigned)f2bf(acch[q*8+5]) << 16);
    u.w = f2bf(acch[q*8+6]) | ((unsigned)f2bf(acch[q*8+7]) << 16);
    *(uint4*)(hrow + q * 8) = u;
  }
  u16* dst = (isf ? fT : gT) + ((size_t)b * NPIX + n0 + pg) * KD + oo;
  #pragma unroll
  for (int p = 0; p < 8; ++p) dst[(size_t)p * KD] = f2bf(accf[p]);
}

// ---------------------------------------------------------------------------
// Kernel 2: s = f^T g, softmax (no max-sub; |s| small), write attn f32 + bf16
// stash. XCD swizzle cpx=256: one batch per XCD -> fT/gT stay in that L2.
// ---------------------------------------------------------------------------
template<bool STASH>
__global__ __launch_bounds__(256) void attn_kernel(
    const u16* __restrict__ fT, const u16* __restrict__ gT,
    float* __restrict__ attn_out, u16* __restrict__ attn_b16)
{
  const int bid = blockIdx.x;
  const int swz = (bid & 7) * 256 + (bid >> 3);   // 2048 = 8 * 256, bijective
  const int b  = swz >> 8;
  const int i0 = (swz & 255) * 16;
  const int t = threadIdx.x;
  const int w = t >> 6, l = t & 63;
  const int lg = l >> 4, lm = l & 15;

  const u16* fb = fT + ((size_t)b * NPIX + i0) * KD;
  const u16* gb = gT + (size_t)b * NPIX * KD;
  short8 af = *(const short8*)(fb + lm * KD + lg * 8);
  f32x4 zero4 = {0.f, 0.f, 0.f, 0.f};

  float sum[4] = {0.f, 0.f, 0.f, 0.f};
  const int jbase = w * 1024;
  for (int jt = 0; jt < 64; ++jt) {
    int j0 = jbase + jt * 16;
    short8 bg8 = *(const short8*)(gb + (size_t)(j0 + lm) * KD + lg * 8);
    f32x4 s = __builtin_amdgcn_mfma_f32_16x16x32_bf16(af, bg8, zero4, 0, 0, 0);
    #pragma unroll
    for (int r = 0; r < 4; ++r) sum[r] += __expf(s[r]);
  }
  #pragma unroll
  for (int m = 1; m < 16; m <<= 1) {
    #pragma unroll
    for (int r = 0; r < 4; ++r) sum[r] += __shfl_xor(sum[r], m, 64);
  }
  __shared__ float part[4][16];
  __shared__ float invs[16];
  if (lm == 0) {
    #pragma unroll
    for (int r = 0; r < 4; ++r) part[w][lg * 4 + r] = sum[r];
  }
  __syncthreads();
  if (t < 16) invs[t] = 1.0f / (part[0][t] + part[1][t] + part[2][t] + part[3][t]);
  __syncthreads();
  float is4[4];
  #pragma unroll
  for (int r = 0; r < 4; ++r) is4[r] = invs[lg * 4 + r];

  float* arow = attn_out + ((size_t)b * NPIX + i0) * NPIX;
  u16*   brow = attn_b16 + ((size_t)b * NPIX + i0) * NPIX;
  for (int jt = 0; jt < 64; ++jt) {
    int j0 = jbase + jt * 16;
    short8 bg8 = *(const short8*)(gb + (size_t)(j0 + lm) * KD + lg * 8);
    f32x4 s = __builtin_amdgcn_mfma_f32_16x16x32_bf16(af, bg8, zero4, 0, 0, 0);
    #pragma unroll
    for (int r = 0; r < 4; ++r) {
      float v = __expf(s[r]) * is4[r];
      int i = lg * 4 + r;
      arow[(size_t)i * NPIX + j0 + lm] = v;
      if (STASH) brow[(size_t)i * NPIX + j0 + lm] = f2bf(v);
    }
  }
}

// ---------------------------------------------------------------------------
// Kernel 3: out[b][c][i] = gamma * sum_j hh[c][j]*attn[i][j] + x[b][c][i]
// Barrier-free all-register GEMM: no LDS, no __syncthreads. Each lane loads
// its MFMA fragments directly from global (A rows wave-private; B-frag =
// lane-contiguous 16B, 4 lanes/row -> 64B runs). Named ping-pong frag
// buffers (static indexing, rule #20) -> compiler emits counted-vmcnt
// software pipeline; cold-HBM B latency hides under MFMAs + TLP instead of
// being drained at a barrier every K-step. XCD swizzle cpx=64: batch<->XCD,
// hh (2 MB/batch) pinned in that XCD's L2 across its 64 blocks.
// ---------------------------------------------------------------------------
template<bool BF16B>
__global__ __launch_bounds__(256) void pv_kernel(
    const u16* __restrict__ hhb, const u16* __restrict__ attn_b16,
    const float* __restrict__ attn_f32, const float* __restrict__ x,
    const float* __restrict__ gamma, float* __restrict__ outp)
{
  const int bid = blockIdx.x;
  const int swz = (bid & 7) * 64 + (bid >> 3);    // 512 = 8 * 64, bijective
  const int b  = swz >> 6;
  const int n0 = (swz & 63) * 64;
  const int t = threadIdx.x;
  const int w = t >> 6, l = t & 63;
  const int lg = l >> 4, lm = l & 15;
  const int kl = lg * 8;                          // k-offset of this lane's slice

  // A: hh rows (w*64 + mf*16 + lm), wave-private. B: attn rows (n0 + nf*16 + lm).
  const u16* Abase  = hhb + ((size_t)b * CH + w * 64 + lm) * NPIX + kl;
  const u16* Bb16   = attn_b16 + ((size_t)b * NPIX + n0 + lm) * NPIX + kl;
  const float* Bf32 = attn_f32 + ((size_t)b * NPIX + n0 + lm) * NPIX + kl;

  f32x4 zero4 = {0.f, 0.f, 0.f, 0.f};
  f32x4 acc[4][4];
  #pragma unroll
  for (int mf = 0; mf < 4; ++mf)
    #pragma unroll
    for (int nf = 0; nf < 4; ++nf) acc[mf][nf] = zero4;

  short8 aA[4], bA[4], aB[4], bB[4];

#define LD_A(DST, K0)                                                         \
  { _Pragma("unroll")                                                         \
    for (int mf = 0; mf < 4; ++mf)                                            \
      DST[mf] = *(const short8*)(Abase + (size_t)(mf * 16) * NPIX + (K0)); }

#define LD_B(DST, K0)                                                         \
  { if (BF16B) {                                                              \
      _Pragma("unroll")                                                       \
      for (int nf = 0; nf < 4; ++nf)                                          \
        DST[nf] = *(const short8*)(Bb16 + (size_t)(nf * 16) * NPIX + (K0));   \
    } else {                                                                  \
      _Pragma("unroll")                                                       \
      for (int nf = 0; nf < 4; ++nf) {                                        \
        const float* sp = Bf32 + (size_t)(nf * 16) * NPIX + (K0);             \
        float4 v0 = *(const float4*)sp;                                       \
        float4 v1 = *(const float4*)(sp + 4);                                 \
        short8 r;                                                             \
        r[0] = (short)f2bf(v0.x); r[1] = (short)f2bf(v0.y);                   \
        r[2] = (short)f2bf(v0.z); r[3] = (short)f2bf(v0.w);                   \
        r[4] = (short)f2bf(v1.x); r[5] = (short)f2bf(v1.y);                   \
        r[6] = (short)f2bf(v1.z); r[7] = (short)f2bf(v1.w);                   \
        DST[nf] = r;                                                          \
      }                                                                       \
    } }

#define MFMA16(AF, BF)                                                        \
  { _Pragma("unroll")                                                         \
    for (int mf = 0; mf < 4; ++mf)                                            \
      _Pragma("unroll")                                                       \
      for (int nf = 0; nf < 4; ++nf)                                          \
        acc[mf][nf] = __builtin_amdgcn_mfma_f32_16x16x32_bf16(                \
            AF[mf], BF[nf], acc[mf][nf], 0, 0, 0); }

  LD_A(aA, 0)
  LD_B(bA, 0)
  for (int k0 = 0; k0 < NPIX; k0 += 64) {
    LD_A(aB, k0 + 32)          // always in range: max k0+32 = 4064
    LD_B(bB, k0 + 32)
    MFMA16(aA, bA)
    if (k0 + 64 < NPIX) {
      LD_A(aA, k0 + 64)
      LD_B(bA, k0 + 64)
    }
    MFMA16(aB, bB)
  }
#undef LD_A
#undef LD_B
#undef MFMA16

  const float gm = gamma[0];
  #pragma unroll
  for (int mf = 0; mf < 4; ++mf) {
    #pragma unroll
    for (int r = 0; r < 4; ++r) {
      int c = w * 64 + mf * 16 + lg * 4 + r;
      #pragma unroll
      for (int nf = 0; nf < 4; ++nf) {
        int i = n0 + nf * 16 + lm;
        size_t idx = ((size_t)b * CH + c) * NPIX + i;
        outp[idx] = fmaf(gm, acc[mf][nf][r], x[idx]);
      }
    }
  }
}

// ---------------------------------------------------------------------------
extern "C" void kernel_launch(void* const* d_in, const int* in_sizes, int n_in,
                              void* d_out, int out_size, void* d_ws, size_t ws_size,
                              hipStream_t stream) {
  const float* x     = (const float*)d_in[0];
  const float* Wf    = (const float*)d_in[1];
  const float* bf    = (const float*)d_in[2];
  const float* Wg    = (const float*)d_in[3];
  const float* bg    = (const float*)d_in[4];
  const float* Wh    = (const float*)d_in[5];
  const float* bh    = (const float*)d_in[6];
  const float* gamma = (const float*)d_in[7];

  float* outp = (float*)d_out;
  float* attn_out = outp + (size_t)BATCH * CH * NPIX;   // out | attention

  u16* fT = (u16*)d_ws;
  u16* gT = fT + (size_t)BATCH * NPIX * KD;
  u16* hh = gT + (size_t)BATCH * NPIX * KD;
  u16* ast = hh + (size_t)BATCH * CH * NPIX;
  const size_t need_full = (size_t)2 * BATCH * NPIX * KD * 2
                         + (size_t)BATCH * CH * NPIX * 2
                         + (size_t)BATCH * NPIX * NPIX * 2;
  const bool stash = ws_size >= need_full;

  proj_kernel<<<dim3(BATCH * (NPIX / 32)), dim3(256), 0, stream>>>(
      x, Wf, bf, Wg, bg, Wh, bh, fT, gT, hh);

  if (stash) {
    attn_kernel<true><<<dim3(BATCH * (NPIX / 16)), dim3(256), 0, stream>>>(
        fT, gT, attn_out, ast);
    pv_kernel<true><<<dim3(BATCH * (NPIX / 64)), dim3(256), 0, stream>>>(
        hh, ast, attn_out, x, gamma, outp);
  } else {
    attn_kernel<false><<<dim3(BATCH * (NPIX / 16)), dim3(256), 0, stream>>>(
        fT, gT, attn_out, ast);
    pv_kernel<false><<<dim3(BATCH * (NPIX / 64)), dim3(256), 0, stream>>>(
        hh, ast, attn_out, x, gamma, outp);
  }
}

// Round 4
// 388.069 us; speedup vs baseline: 1.6909x; 1.6909x over previous
//
#include <hip/hip_runtime.h>
#include <hip/hip_bf16.h>

typedef unsigned short u16;
typedef __attribute__((ext_vector_type(8))) short short8;  // 8 bf16 (4 VGPRs)
typedef __attribute__((ext_vector_type(4))) float f32x4;

#define BATCH 8
#define CH 256
#define NPIX 4096
#define KD 32   // C/8

static __device__ __forceinline__ u16 f2bf(float f) {
  union { __hip_bfloat16 h; u16 u; } cv;
  cv.h = __float2bfloat16(f);
  return cv.u;
}

// ---------------------------------------------------------------------------
// Kernel 1: projections. x [B][C][N] f32 -> fT/gT [B][N][32] bf16, hh [B][C][N] bf16
// Block: 256 threads, one batch x 32-pixel tile. x tile in LDS (broadcast
// reads); weights read as float4 per lane (4x fewer gather insts than scalar).
// ---------------------------------------------------------------------------
__global__ __launch_bounds__(256) void proj_kernel(
    const float* __restrict__ x,
    const float* __restrict__ Wf, const float* __restrict__ bfp,
    const float* __restrict__ Wg, const float* __restrict__ bgp,
    const float* __restrict__ Wh, const float* __restrict__ bhp,
    u16* __restrict__ fT, u16* __restrict__ gT, u16* __restrict__ hhb)
{
  __shared__ float xs[CH][36];
  const int b  = blockIdx.x >> 7;
  const int n0 = (blockIdx.x & 127) * 32;
  const int t  = threadIdx.x;

  const float* xb = x + ((size_t)b * CH) * NPIX + n0;
  #pragma unroll
  for (int kk = 0; kk < 8; ++kk) {
    int v = kk * 256 + t;
    int c = v >> 3, p4 = v & 7;
    float4 d = *(const float4*)(xb + (size_t)c * NPIX + p4 * 4);
    *(float4*)&xs[c][p4 * 4] = d;
  }
  __syncthreads();

  const int o = t;
  float acch[32];
  #pragma unroll
  for (int p = 0; p < 32; ++p) acch[p] = bhp[o];

  const int o2 = t & 63;
  const int oo = o2 & 31;
  const bool isf = o2 < 32;
  const float* Wfg = isf ? Wf : Wg;
  const float bias2 = isf ? bfp[oo] : bgp[oo];
  const int pg = (t >> 6) * 8;
  float accf[8];
  #pragma unroll
  for (int p = 0; p < 8; ++p) accf[p] = bias2;

  const float* whr  = Wh  + o * CH;
  const float* wfgr = Wfg + oo * CH;
  for (int c = 0; c < CH; c += 4) {
    float4 wh4 = *(const float4*)(whr + c);
    float4 wf4 = *(const float4*)(wfgr + c);
    float wha[4] = {wh4.x, wh4.y, wh4.z, wh4.w};
    float wfa[4] = {wf4.x, wf4.y, wf4.z, wf4.w};
    #pragma unroll
    for (int cc = 0; cc < 4; ++cc) {
      float wh = wha[cc], wf = wfa[cc];
      #pragma unroll
      for (int p4 = 0; p4 < 8; ++p4) {
        float4 xv = *(const float4*)&xs[c + cc][p4 * 4];
        acch[p4*4+0] = fmaf(wh, xv.x, acch[p4*4+0]);
        acch[p4*4+1] = fmaf(wh, xv.y, acch[p4*4+1]);
        acch[p4*4+2] = fmaf(wh, xv.z, acch[p4*4+2]);
        acch[p4*4+3] = fmaf(wh, xv.w, acch[p4*4+3]);
      }
      #pragma unroll
      for (int p = 0; p < 8; ++p) accf[p] = fmaf(wf, xs[c + cc][pg + p], accf[p]);
    }
  }

  u16* hrow = hhb + ((size_t)b * CH + o) * NPIX + n0;
  #pragma unroll
  for (int q = 0; q < 4; ++q) {
    uint4 u;
    u.x = f2bf(acch[q*8+0]) | ((unsigned)f2bf(acch[q*8+1]) << 16);
    u.y = f2bf(acch[q*8+2]) | ((unsigned)f2bf(acch[q*8+3]) << 16);
    u.z = f2bf(acch[q*8+4]) | ((unsigned)f2bf(acch[q*8+5]) << 16);
    u.w = f2bf(acch[q*8+6]) | ((unsigned)f2bf(acch[q*8+7]) << 16);
    *(uint4*)(hrow + q * 8) = u;
  }
  u16* dst = (isf ? fT : gT) + ((size_t)b * NPIX + n0 + pg) * KD + oo;
  #pragma unroll
  for (int p = 0; p < 8; ++p) dst[(size_t)p * KD] = f2bf(accf[p]);
}

// ---------------------------------------------------------------------------
// Kernel 2 (fused attn + PV): per block = one batch x 64-row i-stripe.
// 512 threads = 8 waves.
// Pass 1: rowsums of exp(s) (wave iw covers j in [iw*512, +512), all 4 i-tiles).
// Pass 2: per 32-j chunk: wave iw recomputes s-tile (i-tile iw>>2?? no: iw>>1,
//   j-sub iw&1), writes normalized f32 attention to d_out, writes bf16 P^T into
//   XOR-swizzled ping-pong LDS; after a raw lgkm barrier all 8 waves run PV
//   MFMAs (wave iw owns c-rows iw*32..+32) accumulating out[256 x 64].
// hh[b] (2MB) and gT[b] (2MB) are XCD-L2-pinned via b = bid & 7 (round-robin).
// No bf16 stash, no attn re-read from HBM: saves ~536 MB of traffic.
// ---------------------------------------------------------------------------
__global__ __launch_bounds__(512, 4) void fused_attn_pv(
    const u16* __restrict__ fT, const u16* __restrict__ gT,
    const u16* __restrict__ hhb, const float* __restrict__ x,
    const float* __restrict__ gamma,
    float* __restrict__ attn_out, float* __restrict__ outp)
{
  __shared__ u16 Pt[2][64 * 32];    // ping-pong P^T tiles, 4KB each
  __shared__ float part[8][64];
  __shared__ float invs[64];

  const int bid = blockIdx.x;
  const int b  = bid & 7;            // round-robin XCD: batch <-> XCD
  const int n0 = (bid >> 3) * 64;    // i-stripe base
  const int t  = threadIdx.x;
  const int iw = t >> 6, l = t & 63;
  const int lg = l >> 4, lm = l & 15;

  const u16* fb = fT + ((size_t)b * NPIX + n0) * KD;
  const u16* gb = gT + (size_t)b * NPIX * KD;
  const u16* hb = hhb + (size_t)b * CH * NPIX;

  f32x4 z4 = {0.f, 0.f, 0.f, 0.f};

  // f fragments for all 4 i-tiles of this stripe
  short8 ff[4];
  #pragma unroll
  for (int it = 0; it < 4; ++it)
    ff[it] = *(const short8*)(fb + (it * 16 + lm) * KD + lg * 8);

  // ---- pass 1: rowsums ----
  float sum[4][4];
  #pragma unroll
  for (int it = 0; it < 4; ++it)
    #pragma unroll
    for (int r = 0; r < 4; ++r) sum[it][r] = 0.f;

  const int j1 = iw * 512;
  for (int jt = 0; jt < 32; ++jt) {
    int j0 = j1 + jt * 16;
    short8 gf = *(const short8*)(gb + (size_t)(j0 + lm) * KD + lg * 8);
    #pragma unroll
    for (int it = 0; it < 4; ++it) {
      f32x4 s = __builtin_amdgcn_mfma_f32_16x16x32_bf16(ff[it], gf, z4, 0, 0, 0);
      #pragma unroll
      for (int r = 0; r < 4; ++r) sum[it][r] += __expf(s[r]);
    }
  }
  #pragma unroll
  for (int m = 1; m < 16; m <<= 1)
    #pragma unroll
    for (int it = 0; it < 4; ++it)
      #pragma unroll
      for (int r = 0; r < 4; ++r) sum[it][r] += __shfl_xor(sum[it][r], m, 64);
  if (lm == 0) {
    #pragma unroll
    for (int it = 0; it < 4; ++it)
      #pragma unroll
      for (int r = 0; r < 4; ++r) part[iw][it * 16 + lg * 4 + r] = sum[it][r];
  }
  __syncthreads();
  if (t < 64) {
    float s = 0.f;
    #pragma unroll
    for (int w2 = 0; w2 < 8; ++w2) s += part[w2][t];
    invs[t] = 1.0f / s;
  }
  __syncthreads();

  // ---- pass 2 setup ----
  const int it2 = iw >> 1, jsub = iw & 1;
  float inv4[4];
  #pragma unroll
  for (int r = 0; r < 4; ++r) inv4[r] = invs[it2 * 16 + lg * 4 + r];
  const short8 f2 = ff[it2];

  float* arow = attn_out + ((size_t)b * NPIX + n0 + it2 * 16 + lg * 4) * NPIX;
  const int rslot = ((lg ^ ((lm >> 1) & 3)) * 16);  // swizzled B-frag read offset

  f32x4 acc[2][4];
  #pragma unroll
  for (int mf = 0; mf < 2; ++mf)
    #pragma unroll
    for (int nf = 0; nf < 4; ++nf) acc[mf][nf] = z4;

  auto chunk = [&](u16* bufp, int JC) {
    const int j0 = JC + jsub * 16;
    short8 gf = *(const short8*)(gb + (size_t)(j0 + lm) * KD + lg * 8);
    f32x4 s = __builtin_amdgcn_mfma_f32_16x16x32_bf16(f2, gf, z4, 0, 0, 0);
    #pragma unroll
    for (int r = 0; r < 4; ++r) {
      float p = __expf(s[r]) * inv4[r];
      arow[(size_t)r * NPIX + j0 + lm] = p;               // f32 attention out
      int iloc = it2 * 16 + lg * 4 + r;
      int jloc = jsub * 16 + lm;
      int byte = iloc * 64 + ((jloc * 2) ^ (((iloc >> 1) & 3) << 4));
      *(u16*)((char*)bufp + byte) = f2bf(p);              // bf16 P^T to LDS
    }
    // raw barrier: wait LDS writes only (do NOT drain the f32 attn stores)
    asm volatile("s_waitcnt lgkmcnt(0)\n\ts_barrier" ::: "memory");
    short8 af0 = *(const short8*)(hb + (size_t)(iw * 32 + lm) * NPIX + JC + lg * 8);
    short8 af1 = *(const short8*)(hb + (size_t)(iw * 32 + 16 + lm) * NPIX + JC + lg * 8);
    #pragma unroll
    for (int nf = 0; nf < 4; ++nf) {
      short8 bf8 = *(const short8*)((char*)bufp + (nf * 16 + lm) * 64 + rslot);
      acc[0][nf] = __builtin_amdgcn_mfma_f32_16x16x32_bf16(af0, bf8, acc[0][nf], 0, 0, 0);
      acc[1][nf] = __builtin_amdgcn_mfma_f32_16x16x32_bf16(af1, bf8, acc[1][nf], 0, 0, 0);
    }
  };

  for (int jc = 0; jc < NPIX; jc += 64) {
    chunk(&Pt[0][0], jc);
    chunk(&Pt[1][0], jc + 32);
  }

  // ---- epilogue ----
  const float gm = gamma[0];
  #pragma unroll
  for (int mf = 0; mf < 2; ++mf) {
    #pragma unroll
    for (int r = 0; r < 4; ++r) {
      int c = iw * 32 + mf * 16 + lg * 4 + r;
      #pragma unroll
      for (int nf = 0; nf < 4; ++nf) {
        int i = n0 + nf * 16 + lm;
        size_t idx = ((size_t)b * CH + c) * NPIX + i;
        outp[idx] = fmaf(gm, acc[mf][nf][r], x[idx]);
      }
    }
  }
}

// ---------------------------------------------------------------------------
extern "C" void kernel_launch(void* const* d_in, const int* in_sizes, int n_in,
                              void* d_out, int out_size, void* d_ws, size_t ws_size,
                              hipStream_t stream) {
  const float* x     = (const float*)d_in[0];
  const float* Wf    = (const float*)d_in[1];
  const float* bf    = (const float*)d_in[2];
  const float* Wg    = (const float*)d_in[3];
  const float* bg    = (const float*)d_in[4];
  const float* Wh    = (const float*)d_in[5];
  const float* bh    = (const float*)d_in[6];
  const float* gamma = (const float*)d_in[7];

  float* outp = (float*)d_out;
  float* attn_out = outp + (size_t)BATCH * CH * NPIX;   // out | attention

  // ws: fT (2MB) | gT (2MB) | hh (16MB)
  u16* fT = (u16*)d_ws;
  u16* gT = fT + (size_t)BATCH * NPIX * KD;
  u16* hh = gT + (size_t)BATCH * NPIX * KD;

  proj_kernel<<<dim3(BATCH * (NPIX / 32)), dim3(256), 0, stream>>>(
      x, Wf, bf, Wg, bg, Wh, bh, fT, gT, hh);

  fused_attn_pv<<<dim3(BATCH * (NPIX / 64)), dim3(512), 0, stream>>>(
      fT, gT, hh, x, gamma, attn_out, outp);
}

// Round 5
// 326.608 us; speedup vs baseline: 2.0091x; 1.1882x over previous
//
#include <hip/hip_runtime.h>
#include <hip/hip_bf16.h>

typedef unsigned short u16;
typedef __attribute__((ext_vector_type(8))) short short8;  // 8 bf16 (4 VGPRs)
typedef __attribute__((ext_vector_type(4))) float f32x4;

#define BATCH 8
#define CH 256
#define NPIX 4096
#define KD 32   // C/8

static __device__ __forceinline__ u16 f2bf(float f) {
  union { __hip_bfloat16 h; u16 u; } cv;
  cv.h = __float2bfloat16(f);
  return cv.u;
}

// ---------------------------------------------------------------------------
// Kernel 1: projections. x [B][C][N] f32 -> fT/gT [B][N][32] bf16, hh [B][C][N] bf16
// ---------------------------------------------------------------------------
__global__ __launch_bounds__(256) void proj_kernel(
    const float* __restrict__ x,
    const float* __restrict__ Wf, const float* __restrict__ bfp,
    const float* __restrict__ Wg, const float* __restrict__ bgp,
    const float* __restrict__ Wh, const float* __restrict__ bhp,
    u16* __restrict__ fT, u16* __restrict__ gT, u16* __restrict__ hhb)
{
  __shared__ float xs[CH][36];
  const int b  = blockIdx.x >> 7;
  const int n0 = (blockIdx.x & 127) * 32;
  const int t  = threadIdx.x;

  const float* xb = x + ((size_t)b * CH) * NPIX + n0;
  #pragma unroll
  for (int kk = 0; kk < 8; ++kk) {
    int v = kk * 256 + t;
    int c = v >> 3, p4 = v & 7;
    float4 d = *(const float4*)(xb + (size_t)c * NPIX + p4 * 4);
    *(float4*)&xs[c][p4 * 4] = d;
  }
  __syncthreads();

  const int o = t;
  float acch[32];
  #pragma unroll
  for (int p = 0; p < 32; ++p) acch[p] = bhp[o];

  const int o2 = t & 63;
  const int oo = o2 & 31;
  const bool isf = o2 < 32;
  const float* Wfg = isf ? Wf : Wg;
  const float bias2 = isf ? bfp[oo] : bgp[oo];
  const int pg = (t >> 6) * 8;
  float accf[8];
  #pragma unroll
  for (int p = 0; p < 8; ++p) accf[p] = bias2;

  const float* whr  = Wh  + o * CH;
  const float* wfgr = Wfg + oo * CH;
  for (int c = 0; c < CH; c += 4) {
    float4 wh4 = *(const float4*)(whr + c);
    float4 wf4 = *(const float4*)(wfgr + c);
    float wha[4] = {wh4.x, wh4.y, wh4.z, wh4.w};
    float wfa[4] = {wf4.x, wf4.y, wf4.z, wf4.w};
    #pragma unroll
    for (int cc = 0; cc < 4; ++cc) {
      float wh = wha[cc], wf = wfa[cc];
      #pragma unroll
      for (int p4 = 0; p4 < 8; ++p4) {
        float4 xv = *(const float4*)&xs[c + cc][p4 * 4];
        acch[p4*4+0] = fmaf(wh, xv.x, acch[p4*4+0]);
        acch[p4*4+1] = fmaf(wh, xv.y, acch[p4*4+1]);
        acch[p4*4+2] = fmaf(wh, xv.z, acch[p4*4+2]);
        acch[p4*4+3] = fmaf(wh, xv.w, acch[p4*4+3]);
      }
      #pragma unroll
      for (int p = 0; p < 8; ++p) accf[p] = fmaf(wf, xs[c + cc][pg + p], accf[p]);
    }
  }

  u16* hrow = hhb + ((size_t)b * CH + o) * NPIX + n0;
  #pragma unroll
  for (int q = 0; q < 4; ++q) {
    uint4 u;
    u.x = f2bf(acch[q*8+0]) | ((unsigned)f2bf(acch[q*8+1]) << 16);
    u.y = f2bf(acch[q*8+2]) | ((unsigned)f2bf(acch[q*8+3]) << 16);
    u.z = f2bf(acch[q*8+4]) | ((unsigned)f2bf(acch[q*8+5]) << 16);
    u.w = f2bf(acch[q*8+6]) | ((unsigned)f2bf(acch[q*8+7]) << 16);
    *(uint4*)(hrow + q * 8) = u;
  }
  u16* dst = (isf ? fT : gT) + ((size_t)b * NPIX + n0 + pg) * KD + oo;
  #pragma unroll
  for (int p = 0; p < 8; ++p) dst[(size_t)p * KD] = f2bf(accf[p]);
}

// ---------------------------------------------------------------------------
// Kernel 2 (fused attn + PV), pipelined:
//  - 64-j chunks (64 barriers/block instead of 128; 16 PV MFMA/wave/barrier)
//  - g(t+1)/hh(t+1) global loads issued BEFORE the barrier into named
//    ping-pong registers -> ride vmcnt across the barrier (only lgkmcnt(0)
//    drained), ~a full chunk of latency cover.
//  - attention f32 stores are non-temporal (537MB write-once; keep hh/gT in L2)
//  - P^T LDS tile [64i][64j] bf16 with 3-bit XOR swizzle (iloc&7)<<4 on the
//    16B granule -> 2-way (free) on PV ds_read_b128.
// ---------------------------------------------------------------------------
__global__ __launch_bounds__(512, 4) void fused_attn_pv(
    const u16* __restrict__ fT, const u16* __restrict__ gT,
    const u16* __restrict__ hhb, const float* __restrict__ x,
    const float* __restrict__ gamma,
    float* __restrict__ attn_out, float* __restrict__ outp)
{
  __shared__ u16 Pt[2][64 * 64];    // ping-pong P^T tiles, 8KB each
  __shared__ float part[8][64];
  __shared__ float invs[64];

  const int bid = blockIdx.x;
  const int b  = bid & 7;            // round-robin XCD: batch <-> XCD
  const int n0 = (bid >> 3) * 64;    // i-stripe base
  const int t  = threadIdx.x;
  const int iw = t >> 6, l = t & 63;
  const int lg = l >> 4, lm = l & 15;

  const u16* fb = fT + ((size_t)b * NPIX + n0) * KD;
  const u16* gb = gT + (size_t)b * NPIX * KD;
  const u16* hb = hhb + (size_t)b * CH * NPIX;

  f32x4 z4 = {0.f, 0.f, 0.f, 0.f};

  short8 ff[4];
  #pragma unroll
  for (int it = 0; it < 4; ++it)
    ff[it] = *(const short8*)(fb + (it * 16 + lm) * KD + lg * 8);

  // ---- pass 1: rowsums of exp(s) ----
  float sum[4][4];
  #pragma unroll
  for (int it = 0; it < 4; ++it)
    #pragma unroll
    for (int r = 0; r < 4; ++r) sum[it][r] = 0.f;

  const int j1 = iw * 512;
  for (int jt = 0; jt < 32; ++jt) {
    int j0 = j1 + jt * 16;
    short8 gf = *(const short8*)(gb + (size_t)(j0 + lm) * KD + lg * 8);
    #pragma unroll
    for (int it = 0; it < 4; ++it) {
      f32x4 s = __builtin_amdgcn_mfma_f32_16x16x32_bf16(ff[it], gf, z4, 0, 0, 0);
      #pragma unroll
      for (int r = 0; r < 4; ++r) sum[it][r] += __expf(s[r]);
    }
  }
  #pragma unroll
  for (int m = 1; m < 16; m <<= 1)
    #pragma unroll
    for (int it = 0; it < 4; ++it)
      #pragma unroll
      for (int r = 0; r < 4; ++r) sum[it][r] += __shfl_xor(sum[it][r], m, 64);
  if (lm == 0) {
    #pragma unroll
    for (int it = 0; it < 4; ++it)
      #pragma unroll
      for (int r = 0; r < 4; ++r) part[iw][it * 16 + lg * 4 + r] = sum[it][r];
  }
  __syncthreads();
  if (t < 64) {
    float s = 0.f;
    #pragma unroll
    for (int w2 = 0; w2 < 8; ++w2) s += part[w2][t];
    invs[t] = 1.0f / s;
  }
  __syncthreads();

  // ---- pass 2 ----
  const int it2 = iw >> 1, jsub = iw & 1;
  float inv4[4];
  #pragma unroll
  for (int r = 0; r < 4; ++r) inv4[r] = invs[it2 * 16 + lg * 4 + r];
  const short8 f2 = ff[it2];

  float* arow = attn_out + ((size_t)b * NPIX + n0 + it2 * 16 + lg * 4) * NPIX;

  f32x4 acc[2][4];
  #pragma unroll
  for (int mf = 0; mf < 2; ++mf)
    #pragma unroll
    for (int nf = 0; nf < 4; ++nf) acc[mf][nf] = z4;

  short8 gP[2], gQ[2], hP[2][2], hQ[2][2];

  // load g-frags (2 stiles) + hh-frags (2 m x 2 ks) for chunk at JC
  auto LDG = [&](short8 (&g2)[2], short8 (&h2)[2][2], int JC) {
    #pragma unroll
    for (int st = 0; st < 2; ++st)
      g2[st] = *(const short8*)(gb + (size_t)(JC + jsub * 32 + st * 16 + lm) * KD + lg * 8);
    #pragma unroll
    for (int m = 0; m < 2; ++m)
      #pragma unroll
      for (int ks = 0; ks < 2; ++ks)
        h2[m][ks] = *(const short8*)(hb + (size_t)(iw * 32 + m * 16 + lm) * NPIX
                                     + JC + ks * 32 + lg * 8);
  };

  // one 64-j chunk: produce P into buf using gc, prefetch (gn,hn)@JN,
  // barrier, PV with hc.
  auto HALF = [&](u16* buf, short8 (&gc)[2], short8 (&hc)[2][2],
                  short8 (&gn)[2], short8 (&hn)[2][2], int JC, int JN) {
    f32x4 s[2];
    #pragma unroll
    for (int st = 0; st < 2; ++st)
      s[st] = __builtin_amdgcn_mfma_f32_16x16x32_bf16(f2, gc[st], z4, 0, 0, 0);
    LDG(gn, hn, JN);                       // in flight across the barrier
    #pragma unroll
    for (int st = 0; st < 2; ++st) {
      const int j0 = JC + jsub * 32 + st * 16;
      #pragma unroll
      for (int r = 0; r < 4; ++r) {
        float p = __expf(s[st][r]) * inv4[r];
        __builtin_nontemporal_store(p, arow + (size_t)r * NPIX + j0 + lm);
        int iloc = it2 * 16 + lg * 4 + r;
        int jloc = jsub * 32 + st * 16 + lm;
        int byte = iloc * 128 + ((jloc * 2) ^ (((lg * 4 + r) & 7) << 4));
        *(u16*)((char*)buf + byte) = f2bf(p);
      }
    }
    asm volatile("s_waitcnt lgkmcnt(0)\n\ts_barrier" ::: "memory");
    #pragma unroll
    for (int nf = 0; nf < 4; ++nf) {
      #pragma unroll
      for (int ks = 0; ks < 2; ++ks) {
        int byte = (nf * 16 + lm) * 128 + (((ks * 4 + lg) * 16) ^ ((lm & 7) << 4));
        short8 pf = *(const short8*)((char*)buf + byte);
        acc[0][nf] = __builtin_amdgcn_mfma_f32_16x16x32_bf16(hc[0][ks], pf, acc[0][nf], 0, 0, 0);
        acc[1][nf] = __builtin_amdgcn_mfma_f32_16x16x32_bf16(hc[1][ks], pf, acc[1][nf], 0, 0, 0);
      }
    }
  };

  LDG(gP, hP, 0);
  for (int jc = 0; jc < NPIX; jc += 128) {
    int n1 = (jc + 64) & (NPIX - 1);
    int n2 = (jc + 128) & (NPIX - 1);   // wraps to 0 on last iter (harmless)
    HALF(&Pt[0][0], gP, hP, gQ, hQ, jc, n1);
    HALF(&Pt[1][0], gQ, hQ, gP, hP, jc + 64, n2);
  }

  // ---- epilogue ----
  const float gm = gamma[0];
  #pragma unroll
  for (int mf = 0; mf < 2; ++mf) {
    #pragma unroll
    for (int r = 0; r < 4; ++r) {
      int c = iw * 32 + mf * 16 + lg * 4 + r;
      #pragma unroll
      for (int nf = 0; nf < 4; ++nf) {
        int i = n0 + nf * 16 + lm;
        size_t idx = ((size_t)b * CH + c) * NPIX + i;
        outp[idx] = fmaf(gm, acc[mf][nf][r], x[idx]);
      }
    }
  }
}

// ---------------------------------------------------------------------------
extern "C" void kernel_launch(void* const* d_in, const int* in_sizes, int n_in,
                              void* d_out, int out_size, void* d_ws, size_t ws_size,
                              hipStream_t stream) {
  const float* x     = (const float*)d_in[0];
  const float* Wf    = (const float*)d_in[1];
  const float* bf    = (const float*)d_in[2];
  const float* Wg    = (const float*)d_in[3];
  const float* bg    = (const float*)d_in[4];
  const float* Wh    = (const float*)d_in[5];
  const float* bh    = (const float*)d_in[6];
  const float* gamma = (const float*)d_in[7];

  float* outp = (float*)d_out;
  float* attn_out = outp + (size_t)BATCH * CH * NPIX;   // out | attention

  // ws: fT (2MB) | gT (2MB) | hh (16MB)
  u16* fT = (u16*)d_ws;
  u16* gT = fT + (size_t)BATCH * NPIX * KD;
  u16* hh = gT + (size_t)BATCH * NPIX * KD;

  proj_kernel<<<dim3(BATCH * (NPIX / 32)), dim3(256), 0, stream>>>(
      x, Wf, bf, Wg, bg, Wh, bh, fT, gT, hh);

  fused_attn_pv<<<dim3(BATCH * (NPIX / 64)), dim3(512), 0, stream>>>(
      fT, gT, hh, x, gamma, attn_out, outp);
}